// Round 1
// baseline (902.954 us; speedup 1.0000x reference)
//
#include <hip/hip_runtime.h>

typedef unsigned short u16;
typedef __bf16 bf16_t;
typedef bf16_t bf16x8 __attribute__((ext_vector_type(8)));
typedef float f32x4 __attribute__((ext_vector_type(4)));

#define T_TOK 8192
#define DIM   1024
#define FF    512
#define NE    16

__device__ __forceinline__ u16 f2bf(float f) {
  union { float f; unsigned u; } v; v.f = f;
  unsigned r = v.u + 0x7FFFu + ((v.u >> 16) & 1u);
  return (u16)(r >> 16);
}

// async global->LDS, 16B per lane; LDS dest = wave-uniform base + lane*16
#define GLL16(g, l) __builtin_amdgcn_global_load_lds( \
    (const __attribute__((address_space(1))) void*)(g), \
    (__attribute__((address_space(3))) void*)(l), 16, 0, 0)

// ---------------- fp32 -> bf16 convert (vectorized) ----------------
__global__ __launch_bounds__(256) void cvt_kernel(const float* __restrict__ src,
                                                  u16* __restrict__ dst, int n4) {
  int i = blockIdx.x * 256 + threadIdx.x;
  if (i >= n4) return;
  float4 v = reinterpret_cast<const float4*>(src)[i];
  ushort4 o;
  o.x = f2bf(v.x); o.y = f2bf(v.y); o.z = f2bf(v.z); o.w = f2bf(v.w);
  reinterpret_cast<ushort4*>(dst)[i] = o;
}

// ---------------- router: fp32 logits, softmax, top-2 ----------------
// one wave per token; lane = (expert e = lane&15, chunk c = lane>>4)
__global__ __launch_bounds__(256) void router_kernel(
    const float* __restrict__ x, const float* __restrict__ gw,
    const float* __restrict__ ebias, float* __restrict__ probs,
    int* __restrict__ topi, float* __restrict__ topw, int* __restrict__ cnt) {
  int t = blockIdx.x * 4 + (threadIdx.x >> 6);
  int lane = threadIdx.x & 63;
  int e = lane & 15, c = lane >> 4;
  const float4* xv = reinterpret_cast<const float4*>(x + (size_t)t * DIM + c * 256);
  const float4* gv = reinterpret_cast<const float4*>(gw + (size_t)e * DIM + c * 256);
  float s = 0.f;
#pragma unroll 8
  for (int i = 0; i < 64; ++i) {
    float4 a = xv[i], b = gv[i];
    s += a.x * b.x + a.y * b.y + a.z * b.z + a.w * b.w;
  }
  s += __shfl_xor(s, 16);
  s += __shfl_xor(s, 32);
  float logit = s + ebias[e];
  float m = logit;
#pragma unroll
  for (int d = 1; d < 16; d <<= 1) m = fmaxf(m, __shfl_xor(m, d));
  float p = __expf(logit - m);
  float sum = p;
#pragma unroll
  for (int d = 1; d < 16; d <<= 1) sum += __shfl_xor(sum, d);
  float prob = p / sum;
  if (lane < 16) probs[(size_t)t * NE + lane] = prob;
  // top-2 with lowest-index tie-break (matches lax.top_k)
  float b1 = -1.f, b2 = -1.f; int i1 = 0, i2 = 0;
#pragma unroll
  for (int i = 0; i < 16; ++i) {
    float pi = __shfl(prob, i);
    if (pi > b1) { b2 = b1; i2 = i1; b1 = pi; i1 = i; }
    else if (pi > b2) { b2 = pi; i2 = i; }
  }
  if (lane == 0) {
    float ws = b1 + b2;
    topi[t * 2] = i1; topi[t * 2 + 1] = i2;
    topw[t * 2] = b1 / ws; topw[t * 2 + 1] = b2 / ws;
    atomicAdd(&cnt[i1], 1); atomicAdd(&cnt[i2], 1);
  }
}

__global__ void scan_kernel(const int* __restrict__ cnt, int* __restrict__ offs,
                            int* __restrict__ cursor) {
  if (threadIdx.x == 0) {
    int a = 0;
    for (int e = 0; e < NE; ++e) { offs[e] = a; a += cnt[e]; }
    offs[NE] = a;
  }
  if (threadIdx.x < NE) cursor[threadIdx.x] = 0;
}

__global__ __launch_bounds__(256) void scatter_kernel(
    const int* __restrict__ topi, const float* __restrict__ topw,
    const int* __restrict__ offs, int* __restrict__ cursor,
    int* __restrict__ idx, float* __restrict__ cwl) {
  int t = blockIdx.x * 256 + threadIdx.x;
  if (t >= T_TOK) return;
  for (int s = 0; s < 2; ++s) {
    int e = topi[t * 2 + s];
    int p = atomicAdd(&cursor[e], 1);
    idx[offs[e] + p] = t;
    cwl[offs[e] + p] = topw[t * 2 + s];
  }
}

// ---------------- GEMM1 fused: G = silu(A@W1^T) * (A@W3^T), bf16 out ----------------
// A [rows, 1024] bf16, W1/W3 [512,1024] bf16 (per expert if ROUTED). Tile 128x128, BK=32.
template<bool ROUTED>
__global__ __launch_bounds__(256) void gemm_silu_kernel(
    const u16* __restrict__ A, const u16* __restrict__ B1b, const u16* __restrict__ B3b,
    u16* __restrict__ G,
    const int* __restrict__ cnt, const int* __restrict__ offs, const int* __restrict__ gidx) {
  const int K = DIM;
  int e = blockIdx.z;
  int M = T_TOK, rowbase = 0;
  if (ROUTED) {
    M = cnt[e];
    if ((int)blockIdx.x * 128 >= M) return;
    rowbase = offs[e];
  }
  const u16* B1 = B1b + (ROUTED ? (size_t)e * FF * K : 0);
  const u16* B3 = B3b + (ROUTED ? (size_t)e * FF * K : 0);
  int m0 = blockIdx.x * 128, n0 = blockIdx.y * 128;

  __shared__ u16 As[128 * 32], B1s[128 * 32], B3s[128 * 32];

  int tid = threadIdx.x;
  int lane = tid & 63, wv = tid >> 6;
  // staging: thread tid covers LDS bytes tid*16 (round0) and 4096+tid*16 (round1)
  int srow = tid >> 2, sg = tid & 3;
  int sk0 = (sg ^ ((srow >> 1) & 3)) * 8;          // swizzled k-chunk, row srow
  int sk1 = (sg ^ (((srow + 64) >> 1) & 3)) * 8;   // row srow+64
  int r0 = min(m0 + srow, M - 1);
  int r1 = min(m0 + srow + 64, M - 1);
  int ga0 = ROUTED ? gidx[rowbase + r0] : r0;
  int ga1 = ROUTED ? gidx[rowbase + r1] : r1;
  const u16* Ap0 = A + (size_t)ga0 * K + sk0;
  const u16* Ap1 = A + (size_t)ga1 * K + sk1;
  const u16* B1p0 = B1 + (size_t)(n0 + srow) * K + sk0;
  const u16* B1p1 = B1 + (size_t)(n0 + srow + 64) * K + sk1;
  const u16* B3p0 = B3 + (size_t)(n0 + srow) * K + sk0;
  const u16* B3p1 = B3 + (size_t)(n0 + srow + 64) * K + sk1;
  u16* lA0 = As + wv * 512;        u16* lA1 = As + 2048 + wv * 512;
  u16* lB10 = B1s + wv * 512;      u16* lB11 = B1s + 2048 + wv * 512;
  u16* lB30 = B3s + wv * 512;      u16* lB31 = B3s + 2048 + wv * 512;

  int ln15 = lane & 15, qd = lane >> 4;
  int qsw = (qd ^ ((ln15 >> 1) & 3)) * 8;
  int wm = (wv >> 1) * 64, wn = (wv & 1) * 64;
  int aoff = (wm + ln15) * 32 + qsw;
  int boff = (wn + ln15) * 32 + qsw;

  f32x4 acc1[4][4] = {};
  f32x4 acc3[4][4] = {};

  for (int kt = 0; kt < K; kt += 32) {
    GLL16(Ap0 + kt, lA0);  GLL16(Ap1 + kt, lA1);
    GLL16(B1p0 + kt, lB10); GLL16(B1p1 + kt, lB11);
    GLL16(B3p0 + kt, lB30); GLL16(B3p1 + kt, lB31);
    __syncthreads();
    bf16x8 af[4], b1f[4], b3f[4];
#pragma unroll
    for (int i = 0; i < 4; ++i) {
      af[i] = *reinterpret_cast<const bf16x8*>(&As[aoff + i * 512]);
      b1f[i] = *reinterpret_cast<const bf16x8*>(&B1s[boff + i * 512]);
      b3f[i] = *reinterpret_cast<const bf16x8*>(&B3s[boff + i * 512]);
    }
#pragma unroll
    for (int i = 0; i < 4; ++i)
#pragma unroll
      for (int j = 0; j < 4; ++j) {
        acc1[i][j] = __builtin_amdgcn_mfma_f32_16x16x32_bf16(af[i], b1f[j], acc1[i][j], 0, 0, 0);
        acc3[i][j] = __builtin_amdgcn_mfma_f32_16x16x32_bf16(af[i], b3f[j], acc3[i][j], 0, 0, 0);
      }
    __syncthreads();
  }

  int mrem = M - m0;
#pragma unroll
  for (int i = 0; i < 4; ++i)
#pragma unroll
    for (int r = 0; r < 4; ++r) {
      int ml = wm + i * 16 + qd * 4 + r;
      if (ml < mrem) {
        size_t orow = (size_t)(rowbase + m0 + ml);
#pragma unroll
        for (int j = 0; j < 4; ++j) {
          float z1 = acc1[i][j][r], z3 = acc3[i][j][r];
          float g = z1 / (1.f + __expf(-z1)) * z3;
          G[orow * FF + n0 + wn + j * 16 + ln15] = f2bf(g);
        }
      }
    }
}

// ---------------- GEMM2: Y(+)= (G @ W2^T) [* cw, atomic if ROUTED] ----------------
// G [rows,512] bf16, W2 [1024,512] bf16 per expert. K=512, N=1024.
template<bool ROUTED>
__global__ __launch_bounds__(256) void gemm_out_kernel(
    const u16* __restrict__ Gb, const u16* __restrict__ W2b, float* __restrict__ Y,
    const int* __restrict__ cnt, const int* __restrict__ offs,
    const int* __restrict__ gidx, const float* __restrict__ cwl) {
  const int K = FF;
  int e = blockIdx.z;
  int M = T_TOK, rowbase = 0;
  if (ROUTED) {
    M = cnt[e];
    if ((int)blockIdx.x * 128 >= M) return;
    rowbase = offs[e];
  }
  const u16* B = W2b + (ROUTED ? (size_t)e * DIM * K : 0);
  int m0 = blockIdx.x * 128, n0 = blockIdx.y * 128;

  __shared__ u16 As[128 * 32], Bs[128 * 32];

  int tid = threadIdx.x;
  int lane = tid & 63, wv = tid >> 6;
  int srow = tid >> 2, sg = tid & 3;
  int sk0 = (sg ^ ((srow >> 1) & 3)) * 8;
  int sk1 = (sg ^ (((srow + 64) >> 1) & 3)) * 8;
  int r0 = min(m0 + srow, M - 1);
  int r1 = min(m0 + srow + 64, M - 1);
  const u16* Ap0 = Gb + (size_t)(rowbase + r0) * K + sk0;
  const u16* Ap1 = Gb + (size_t)(rowbase + r1) * K + sk1;
  const u16* Bp0 = B + (size_t)(n0 + srow) * K + sk0;
  const u16* Bp1 = B + (size_t)(n0 + srow + 64) * K + sk1;
  u16* lA0 = As + wv * 512;  u16* lA1 = As + 2048 + wv * 512;
  u16* lB0 = Bs + wv * 512;  u16* lB1 = Bs + 2048 + wv * 512;

  int ln15 = lane & 15, qd = lane >> 4;
  int qsw = (qd ^ ((ln15 >> 1) & 3)) * 8;
  int wm = (wv >> 1) * 64, wn = (wv & 1) * 64;
  int aoff = (wm + ln15) * 32 + qsw;
  int boff = (wn + ln15) * 32 + qsw;

  f32x4 acc[4][4] = {};

  for (int kt = 0; kt < K; kt += 32) {
    GLL16(Ap0 + kt, lA0); GLL16(Ap1 + kt, lA1);
    GLL16(Bp0 + kt, lB0); GLL16(Bp1 + kt, lB1);
    __syncthreads();
    bf16x8 af[4], bf[4];
#pragma unroll
    for (int i = 0; i < 4; ++i) {
      af[i] = *reinterpret_cast<const bf16x8*>(&As[aoff + i * 512]);
      bf[i] = *reinterpret_cast<const bf16x8*>(&Bs[boff + i * 512]);
    }
#pragma unroll
    for (int i = 0; i < 4; ++i)
#pragma unroll
      for (int j = 0; j < 4; ++j)
        acc[i][j] = __builtin_amdgcn_mfma_f32_16x16x32_bf16(af[i], bf[j], acc[i][j], 0, 0, 0);
    __syncthreads();
  }

  int mrem = M - m0;
#pragma unroll
  for (int i = 0; i < 4; ++i)
#pragma unroll
    for (int r = 0; r < 4; ++r) {
      int ml = wm + i * 16 + qd * 4 + r;
      if (ml < mrem) {
        if (ROUTED) {
          int lrow = rowbase + m0 + ml;
          int t = gidx[lrow];
          float cw = cwl[lrow];
#pragma unroll
          for (int j = 0; j < 4; ++j)
            atomicAdd(&Y[(size_t)t * DIM + n0 + wn + j * 16 + ln15], acc[i][j][r] * cw);
        } else {
#pragma unroll
          for (int j = 0; j < 4; ++j)
            Y[(size_t)(m0 + ml) * DIM + n0 + wn + j * 16 + ln15] = acc[i][j][r];
        }
      }
    }
}

// ---------------- launcher ----------------
extern "C" void kernel_launch(void* const* d_in, const int* in_sizes, int n_in,
                              void* d_out, int out_size, void* d_ws, size_t ws_size,
                              hipStream_t stream) {
  const float* x     = (const float*)d_in[0];
  const float* gw    = (const float*)d_in[1];
  const float* ebias = (const float*)d_in[2];
  const float* sw1   = (const float*)d_in[3];
  const float* sw2   = (const float*)d_in[4];
  const float* sw3   = (const float*)d_in[5];
  const float* ew1   = (const float*)d_in[6];
  const float* ew2   = (const float*)d_in[7];
  const float* ew3   = (const float*)d_in[8];
  float* y = (float*)d_out;
  float* probs = y + (size_t)T_TOK * DIM;

  char* ws = (char*)d_ws;
  size_t o = 0;
  auto alloc = [&](size_t bytes) -> void* {
    void* p = ws + o;
    o = (o + bytes + 255) & ~(size_t)255;
    return p;
  };
  u16* xb   = (u16*)alloc((size_t)T_TOK * DIM * 2);
  u16* sw1b = (u16*)alloc((size_t)FF * DIM * 2);
  u16* sw2b = (u16*)alloc((size_t)FF * DIM * 2);
  u16* sw3b = (u16*)alloc((size_t)FF * DIM * 2);
  u16* ew1b = (u16*)alloc((size_t)NE * FF * DIM * 2);
  u16* ew2b = (u16*)alloc((size_t)NE * FF * DIM * 2);
  u16* ew3b = (u16*)alloc((size_t)NE * FF * DIM * 2);
  u16* g_s  = (u16*)alloc((size_t)T_TOK * FF * 2);
  u16* g_rt = (u16*)alloc((size_t)2 * T_TOK * FF * 2);
  int*   topi   = (int*)alloc(T_TOK * 2 * 4);
  float* topw   = (float*)alloc(T_TOK * 2 * 4);
  int*   idx    = (int*)alloc(T_TOK * 2 * 4);
  float* cwl    = (float*)alloc(T_TOK * 2 * 4);
  int*   cnt    = (int*)alloc(256);
  int*   offs   = (int*)alloc(256);
  int*   cursor = (int*)alloc(256);

  hipMemsetAsync(cnt, 0, NE * 4, stream);

  cvt_kernel<<<8192, 256, 0, stream>>>(x, xb, T_TOK * DIM / 4);
  cvt_kernel<<<512, 256, 0, stream>>>(sw1, sw1b, FF * DIM / 4);
  cvt_kernel<<<512, 256, 0, stream>>>(sw2, sw2b, FF * DIM / 4);
  cvt_kernel<<<512, 256, 0, stream>>>(sw3, sw3b, FF * DIM / 4);
  cvt_kernel<<<8192, 256, 0, stream>>>(ew1, ew1b, NE * FF * DIM / 4);
  cvt_kernel<<<8192, 256, 0, stream>>>(ew2, ew2b, NE * FF * DIM / 4);
  cvt_kernel<<<8192, 256, 0, stream>>>(ew3, ew3b, NE * FF * DIM / 4);

  router_kernel<<<T_TOK / 4, 256, 0, stream>>>(x, gw, ebias, probs, topi, topw, cnt);
  scan_kernel<<<1, 64, 0, stream>>>(cnt, offs, cursor);
  scatter_kernel<<<T_TOK / 256, 256, 0, stream>>>(topi, topw, offs, cursor, idx, cwl);

  // shared expert
  gemm_silu_kernel<false><<<dim3(64, 4, 1), 256, 0, stream>>>(
      xb, sw1b, sw3b, g_s, nullptr, nullptr, nullptr);
  gemm_out_kernel<false><<<dim3(64, 8, 1), 256, 0, stream>>>(
      g_s, sw2b, y, nullptr, nullptr, nullptr, nullptr);
  // routed experts (sparse, grouped; inactive tiles early-exit)
  gemm_silu_kernel<true><<<dim3(64, 4, NE), 256, 0, stream>>>(
      xb, ew1b, ew3b, g_rt, cnt, offs, idx);
  gemm_out_kernel<true><<<dim3(64, 8, NE), 256, 0, stream>>>(
      g_rt, ew2b, y, cnt, offs, idx, cwl);
}

// Round 2
// 647.213 us; speedup vs baseline: 1.3951x; 1.3951x over previous
//
#include <hip/hip_runtime.h>

typedef unsigned short u16;
typedef __bf16 bf16_t;
typedef bf16_t bf16x8 __attribute__((ext_vector_type(8)));
typedef float f32x4 __attribute__((ext_vector_type(4)));

#define T_TOK 8192
#define DIM   1024
#define FF    512
#define NE    16
#define NSLOT (3 * T_TOK)          // 2 routed + 1 shared slot per token
#define RBASE_SHARED (2 * T_TOK)   // shared group rowbase = 16384
#define NROWS (RBASE_SHARED + T_TOK) // 24576 total row-slots
#define MAXTILES 256

__device__ __forceinline__ u16 f2bf(float f) {
  union { float f; unsigned u; } v; v.f = f;
  unsigned r = v.u + 0x7FFFu + ((v.u >> 16) & 1u);
  return (u16)(r >> 16);
}
__device__ __forceinline__ float bf2f(u16 h) {
  union { unsigned u; float f; } v; v.u = ((unsigned)h) << 16; return v.f;
}

// async global->LDS, 16B per lane; LDS dest = wave-uniform base + lane*16
#define GLL16(g, l) __builtin_amdgcn_global_load_lds( \
    (const __attribute__((address_space(1))) void*)(g), \
    (__attribute__((address_space(3))) void*)(l), 16, 0, 0)

// ---------------- fused fp32 -> bf16 convert for all 7 inputs ----------------
#define X4   2097152   // x: 8192*1024/4
#define SW4  131072    // each shared weight: 512*1024/4
#define EW4  2097152   // each expert weight: 16*512*1024/4
#define TOT4 (X4 + 3 * SW4 + 3 * EW4)

__global__ __launch_bounds__(256) void cvt_all_kernel(
    const float* __restrict__ x, const float* __restrict__ sw1,
    const float* __restrict__ sw2, const float* __restrict__ sw3,
    const float* __restrict__ ew1, const float* __restrict__ ew2,
    const float* __restrict__ ew3,
    u16* __restrict__ xb, u16* __restrict__ sw1b, u16* __restrict__ sw2b,
    u16* __restrict__ sw3b, u16* __restrict__ ew1b, u16* __restrict__ ew2b,
    u16* __restrict__ ew3b) {
  int i = blockIdx.x * 256 + threadIdx.x;
  const float* s; u16* dst; int j;
  if (i < X4)                       { s = x;   dst = xb;   j = i; }
  else if (i < X4 + SW4)            { s = sw1; dst = sw1b; j = i - X4; }
  else if (i < X4 + 2 * SW4)        { s = sw2; dst = sw2b; j = i - (X4 + SW4); }
  else if (i < X4 + 3 * SW4)        { s = sw3; dst = sw3b; j = i - (X4 + 2 * SW4); }
  else if (i < X4 + 3 * SW4 + EW4)      { s = ew1; dst = ew1b; j = i - (X4 + 3 * SW4); }
  else if (i < X4 + 3 * SW4 + 2 * EW4)  { s = ew2; dst = ew2b; j = i - (X4 + 3 * SW4 + EW4); }
  else if (i < TOT4)                    { s = ew3; dst = ew3b; j = i - (X4 + 3 * SW4 + 2 * EW4); }
  else return;
  float4 v = reinterpret_cast<const float4*>(s)[j];
  ushort4 o;
  o.x = f2bf(v.x); o.y = f2bf(v.y); o.z = f2bf(v.z); o.w = f2bf(v.w);
  reinterpret_cast<ushort4*>(dst)[j] = o;
}

// ---------------- router: fp32 logits, softmax, top-2 ----------------
__global__ __launch_bounds__(256) void router_kernel(
    const float* __restrict__ x, const float* __restrict__ gw,
    const float* __restrict__ ebias, float* __restrict__ probs,
    int* __restrict__ topi, float* __restrict__ topw, int* __restrict__ cnt) {
  int t = blockIdx.x * 4 + (threadIdx.x >> 6);
  int lane = threadIdx.x & 63;
  int e = lane & 15, c = lane >> 4;
  const float4* xv = reinterpret_cast<const float4*>(x + (size_t)t * DIM + c * 256);
  const float4* gv = reinterpret_cast<const float4*>(gw + (size_t)e * DIM + c * 256);
  float s = 0.f;
#pragma unroll 8
  for (int i = 0; i < 64; ++i) {
    float4 a = xv[i], b = gv[i];
    s += a.x * b.x + a.y * b.y + a.z * b.z + a.w * b.w;
  }
  s += __shfl_xor(s, 16);
  s += __shfl_xor(s, 32);
  float logit = s + ebias[e];
  float m = logit;
#pragma unroll
  for (int d = 1; d < 16; d <<= 1) m = fmaxf(m, __shfl_xor(m, d));
  float p = __expf(logit - m);
  float sum = p;
#pragma unroll
  for (int d = 1; d < 16; d <<= 1) sum += __shfl_xor(sum, d);
  float prob = p / sum;
  if (lane < 16) probs[(size_t)t * NE + lane] = prob;
  float b1 = -1.f, b2 = -1.f; int i1 = 0, i2 = 0;
#pragma unroll
  for (int i = 0; i < 16; ++i) {
    float pi = __shfl(prob, i);
    if (pi > b1) { b2 = b1; i2 = i1; b1 = pi; i1 = i; }
    else if (pi > b2) { b2 = pi; i2 = i; }
  }
  if (lane == 0) {
    float ws = b1 + b2;
    topi[t * 2] = i1; topi[t * 2 + 1] = i2;
    topw[t * 2] = b1 / ws; topw[t * 2 + 1] = b2 / ws;
    atomicAdd(&cnt[i1], 1); atomicAdd(&cnt[i2], 1);
  }
}

// ---------------- scan: prefix offsets + dense tile table ----------------
__global__ void scan_kernel(const int* __restrict__ cnt, int* __restrict__ offs,
                            int* __restrict__ cursor, int2* __restrict__ tab) {
  if (threadIdx.x == 0) {
    int a = 0;
    for (int e = 0; e < NE; ++e) { offs[e] = a; a += cnt[e]; }
    offs[NE] = RBASE_SHARED;  // shared group rowbase (a == 2*T_TOK always)
    int n = 0;
    for (int e = 0; e <= NE; ++e) {
      int M = (e == NE) ? T_TOK : cnt[e];
      for (int m0 = 0; m0 < M; m0 += 128) { tab[n].x = e; tab[n].y = m0; ++n; }
    }
    for (; n < MAXTILES; ++n) { tab[n].x = -1; tab[n].y = 0; }
  }
  if (threadIdx.x < NE) cursor[threadIdx.x] = 0;
}

// ---------------- scatter tokens to slots (+identity shared slots) ----------------
__global__ __launch_bounds__(256) void scatter_kernel(
    const int* __restrict__ topi, const float* __restrict__ topw,
    const int* __restrict__ offs, int* __restrict__ cursor,
    int* __restrict__ idx, float* __restrict__ cwl, int* __restrict__ slotmap) {
  int t = blockIdx.x * 256 + threadIdx.x;
  if (t >= T_TOK) return;
  for (int s = 0; s < 2; ++s) {
    int e = topi[t * 2 + s];
    int p = atomicAdd(&cursor[e], 1);
    int slot = offs[e] + p;
    idx[slot] = t;
    cwl[slot] = topw[t * 2 + s];
    slotmap[t * 3 + s] = slot;
  }
  int sh = RBASE_SHARED + t;
  idx[sh] = t;
  cwl[sh] = 1.0f;
  slotmap[t * 3 + 2] = sh;
}

// ---------------- grouped GEMM1: G = silu(A@W1^T) * (A@W3^T), bf16 ----------------
// tile table driven; group 16 = shared expert. A gathered via idx. Tile 128x128, BK=32.
__global__ __launch_bounds__(256) void gemm_silu_kernel(
    const u16* __restrict__ A, const u16* __restrict__ sw1b, const u16* __restrict__ sw3b,
    const u16* __restrict__ ew1b, const u16* __restrict__ ew3b, u16* __restrict__ G,
    const int2* __restrict__ tab, const int* __restrict__ offs,
    const int* __restrict__ cnt, const int* __restrict__ gidx) {
  const int K = DIM;
  int2 te = tab[blockIdx.x];
  int e = te.x;
  if (e < 0) return;
  int m0 = te.y;
  int M = (e == NE) ? T_TOK : cnt[e];
  int rowbase = offs[e];
  const u16* B1 = (e == NE) ? sw1b : ew1b + (size_t)e * FF * K;
  const u16* B3 = (e == NE) ? sw3b : ew3b + (size_t)e * FF * K;
  int n0 = blockIdx.y * 128;

  __shared__ u16 As[128 * 32], B1s[128 * 32], B3s[128 * 32];

  int tid = threadIdx.x;
  int lane = tid & 63, wv = tid >> 6;
  int srow = tid >> 2, sg = tid & 3;
  int sk0 = (sg ^ ((srow >> 1) & 3)) * 8;
  int sk1 = (sg ^ (((srow + 64) >> 1) & 3)) * 8;
  int r0 = min(m0 + srow, M - 1);
  int r1 = min(m0 + srow + 64, M - 1);
  int ga0 = gidx[rowbase + r0];
  int ga1 = gidx[rowbase + r1];
  const u16* Ap0 = A + (size_t)ga0 * K + sk0;
  const u16* Ap1 = A + (size_t)ga1 * K + sk1;
  const u16* B1p0 = B1 + (size_t)(n0 + srow) * K + sk0;
  const u16* B1p1 = B1 + (size_t)(n0 + srow + 64) * K + sk1;
  const u16* B3p0 = B3 + (size_t)(n0 + srow) * K + sk0;
  const u16* B3p1 = B3 + (size_t)(n0 + srow + 64) * K + sk1;
  u16* lA0 = As + wv * 512;   u16* lA1 = As + 2048 + wv * 512;
  u16* lB10 = B1s + wv * 512; u16* lB11 = B1s + 2048 + wv * 512;
  u16* lB30 = B3s + wv * 512; u16* lB31 = B3s + 2048 + wv * 512;

  int ln15 = lane & 15, qd = lane >> 4;
  int qsw = (qd ^ ((ln15 >> 1) & 3)) * 8;
  int wm = (wv >> 1) * 64, wn = (wv & 1) * 64;
  int aoff = (wm + ln15) * 32 + qsw;
  int boff = (wn + ln15) * 32 + qsw;

  f32x4 acc1[4][4] = {};
  f32x4 acc3[4][4] = {};

  for (int kt = 0; kt < K; kt += 32) {
    GLL16(Ap0 + kt, lA0);   GLL16(Ap1 + kt, lA1);
    GLL16(B1p0 + kt, lB10); GLL16(B1p1 + kt, lB11);
    GLL16(B3p0 + kt, lB30); GLL16(B3p1 + kt, lB31);
    __syncthreads();
    bf16x8 af[4], b1f[4], b3f[4];
#pragma unroll
    for (int i = 0; i < 4; ++i) {
      af[i]  = *reinterpret_cast<const bf16x8*>(&As[aoff + i * 512]);
      b1f[i] = *reinterpret_cast<const bf16x8*>(&B1s[boff + i * 512]);
      b3f[i] = *reinterpret_cast<const bf16x8*>(&B3s[boff + i * 512]);
    }
#pragma unroll
    for (int i = 0; i < 4; ++i)
#pragma unroll
      for (int j = 0; j < 4; ++j) {
        acc1[i][j] = __builtin_amdgcn_mfma_f32_16x16x32_bf16(af[i], b1f[j], acc1[i][j], 0, 0, 0);
        acc3[i][j] = __builtin_amdgcn_mfma_f32_16x16x32_bf16(af[i], b3f[j], acc3[i][j], 0, 0, 0);
      }
    __syncthreads();
  }

  int mrem = M - m0;
#pragma unroll
  for (int i = 0; i < 4; ++i)
#pragma unroll
    for (int r = 0; r < 4; ++r) {
      int ml = wm + i * 16 + qd * 4 + r;
      if (ml < mrem) {
        size_t orow = (size_t)(rowbase + m0 + ml);
#pragma unroll
        for (int j = 0; j < 4; ++j) {
          float z1 = acc1[i][j][r], z3 = acc3[i][j][r];
          float g = z1 / (1.f + __expf(-z1)) * z3;
          G[orow * FF + n0 + wn + j * 16 + ln15] = f2bf(g);
        }
      }
    }
}

// ---------------- grouped GEMM2: O[slot] = cw * (G @ W2^T), bf16 ----------------
__global__ __launch_bounds__(256) void gemm_out_kernel(
    const u16* __restrict__ Gb, const u16* __restrict__ sw2b, const u16* __restrict__ ew2b,
    u16* __restrict__ O, const int2* __restrict__ tab, const int* __restrict__ offs,
    const int* __restrict__ cnt, const float* __restrict__ cwl) {
  const int K = FF;
  int2 te = tab[blockIdx.x];
  int e = te.x;
  if (e < 0) return;
  int m0 = te.y;
  int M = (e == NE) ? T_TOK : cnt[e];
  int rowbase = offs[e];
  const u16* B = (e == NE) ? sw2b : ew2b + (size_t)e * DIM * K;
  int n0 = blockIdx.y * 128;

  __shared__ u16 As[128 * 32], Bs[128 * 32];

  int tid = threadIdx.x;
  int lane = tid & 63, wv = tid >> 6;
  int srow = tid >> 2, sg = tid & 3;
  int sk0 = (sg ^ ((srow >> 1) & 3)) * 8;
  int sk1 = (sg ^ (((srow + 64) >> 1) & 3)) * 8;
  int r0 = min(m0 + srow, M - 1);
  int r1 = min(m0 + srow + 64, M - 1);
  const u16* Ap0 = Gb + (size_t)(rowbase + r0) * K + sk0;
  const u16* Ap1 = Gb + (size_t)(rowbase + r1) * K + sk1;
  const u16* Bp0 = B + (size_t)(n0 + srow) * K + sk0;
  const u16* Bp1 = B + (size_t)(n0 + srow + 64) * K + sk1;
  u16* lA0 = As + wv * 512; u16* lA1 = As + 2048 + wv * 512;
  u16* lB0 = Bs + wv * 512; u16* lB1 = Bs + 2048 + wv * 512;

  int ln15 = lane & 15, qd = lane >> 4;
  int qsw = (qd ^ ((ln15 >> 1) & 3)) * 8;
  int wm = (wv >> 1) * 64, wn = (wv & 1) * 64;
  int aoff = (wm + ln15) * 32 + qsw;
  int boff = (wn + ln15) * 32 + qsw;

  f32x4 acc[4][4] = {};

  for (int kt = 0; kt < K; kt += 32) {
    GLL16(Ap0 + kt, lA0); GLL16(Ap1 + kt, lA1);
    GLL16(Bp0 + kt, lB0); GLL16(Bp1 + kt, lB1);
    __syncthreads();
    bf16x8 af[4], bf[4];
#pragma unroll
    for (int i = 0; i < 4; ++i) {
      af[i] = *reinterpret_cast<const bf16x8*>(&As[aoff + i * 512]);
      bf[i] = *reinterpret_cast<const bf16x8*>(&Bs[boff + i * 512]);
    }
#pragma unroll
    for (int i = 0; i < 4; ++i)
#pragma unroll
      for (int j = 0; j < 4; ++j)
        acc[i][j] = __builtin_amdgcn_mfma_f32_16x16x32_bf16(af[i], bf[j], acc[i][j], 0, 0, 0);
    __syncthreads();
  }

  int mrem = M - m0;
#pragma unroll
  for (int i = 0; i < 4; ++i)
#pragma unroll
    for (int r = 0; r < 4; ++r) {
      int ml = wm + i * 16 + qd * 4 + r;
      if (ml < mrem) {
        int slot = rowbase + m0 + ml;
        float cw = cwl[slot];
#pragma unroll
        for (int j = 0; j < 4; ++j)
          O[(size_t)slot * DIM + n0 + wn + j * 16 + ln15] = f2bf(acc[i][j][r] * cw);
      }
    }
}

// ---------------- combine: y[t] = sum of token's 3 slot rows ----------------
__global__ __launch_bounds__(256) void combine_kernel(
    const u16* __restrict__ O, const int* __restrict__ slotmap, float* __restrict__ y) {
  int t = blockIdx.x;
  int c = threadIdx.x;  // 256 threads x 4 floats = 1024
  int s0 = slotmap[t * 3], s1 = slotmap[t * 3 + 1], s2 = slotmap[t * 3 + 2];
  ushort4 a = reinterpret_cast<const ushort4*>(O + (size_t)s0 * DIM)[c];
  ushort4 b = reinterpret_cast<const ushort4*>(O + (size_t)s1 * DIM)[c];
  ushort4 d = reinterpret_cast<const ushort4*>(O + (size_t)s2 * DIM)[c];
  float4 r;
  r.x = bf2f(a.x) + bf2f(b.x) + bf2f(d.x);
  r.y = bf2f(a.y) + bf2f(b.y) + bf2f(d.y);
  r.z = bf2f(a.z) + bf2f(b.z) + bf2f(d.z);
  r.w = bf2f(a.w) + bf2f(b.w) + bf2f(d.w);
  reinterpret_cast<float4*>(y + (size_t)t * DIM)[c] = r;
}

// ---------------- launcher ----------------
extern "C" void kernel_launch(void* const* d_in, const int* in_sizes, int n_in,
                              void* d_out, int out_size, void* d_ws, size_t ws_size,
                              hipStream_t stream) {
  const float* x     = (const float*)d_in[0];
  const float* gw    = (const float*)d_in[1];
  const float* ebias = (const float*)d_in[2];
  const float* sw1   = (const float*)d_in[3];
  const float* sw2   = (const float*)d_in[4];
  const float* sw3   = (const float*)d_in[5];
  const float* ew1   = (const float*)d_in[6];
  const float* ew2   = (const float*)d_in[7];
  const float* ew3   = (const float*)d_in[8];
  float* y = (float*)d_out;
  float* probs = y + (size_t)T_TOK * DIM;

  char* ws = (char*)d_ws;
  size_t o = 0;
  auto alloc = [&](size_t bytes) -> char* {
    char* p = ws + o;
    o = (o + bytes + 255) & ~(size_t)255;
    return p;
  };
  u16* G    = (u16*)alloc((size_t)NROWS * FF * 2);        // 25.2 MB
  u16* sw1b = (u16*)alloc((size_t)FF * DIM * 2);
  u16* sw2b = (u16*)alloc((size_t)FF * DIM * 2);
  u16* sw3b = (u16*)alloc((size_t)FF * DIM * 2);
  u16* ew2b = (u16*)alloc((size_t)NE * FF * DIM * 2);     // 16.8 MB
  // aliased region: [xb | ew1b | ew3b] (live through silu) == O (live after silu)
  char* aliasBase = alloc((size_t)NROWS * DIM * 2);       // 50.33 MB
  u16* xb   = (u16*)aliasBase;
  u16* ew1b = (u16*)(aliasBase + (size_t)T_TOK * DIM * 2);
  u16* ew3b = (u16*)(aliasBase + (size_t)T_TOK * DIM * 2 + (size_t)NE * FF * DIM * 2);
  u16* O    = (u16*)aliasBase;
  int*   topi    = (int*)alloc(T_TOK * 2 * 4);
  float* topw    = (float*)alloc(T_TOK * 2 * 4);
  int*   idx     = (int*)alloc(NROWS * 4);
  float* cwl     = (float*)alloc(NROWS * 4);
  int*   slotmap = (int*)alloc(T_TOK * 3 * 4);
  int2*  tab     = (int2*)alloc(MAXTILES * 8);
  int*   cnt     = (int*)alloc(256);
  int*   offs    = (int*)alloc(256);
  int*   cursor  = (int*)alloc(256);

  hipMemsetAsync(cnt, 0, NE * 4, stream);

  cvt_all_kernel<<<TOT4 / 256, 256, 0, stream>>>(x, sw1, sw2, sw3, ew1, ew2, ew3,
                                                 xb, sw1b, sw2b, sw3b, ew1b, ew2b, ew3b);
  router_kernel<<<T_TOK / 4, 256, 0, stream>>>(x, gw, ebias, probs, topi, topw, cnt);
  scan_kernel<<<1, 64, 0, stream>>>(cnt, offs, cursor, tab);
  scatter_kernel<<<T_TOK / 256, 256, 0, stream>>>(topi, topw, offs, cursor, idx, cwl, slotmap);

  gemm_silu_kernel<<<dim3(MAXTILES, 4, 1), 256, 0, stream>>>(
      xb, sw1b, sw3b, ew1b, ew3b, G, tab, offs, cnt, idx);
  gemm_out_kernel<<<dim3(MAXTILES, 8, 1), 256, 0, stream>>>(
      G, sw2b, ew2b, O, tab, offs, cnt, cwl);
  combine_kernel<<<T_TOK, 256, 0, stream>>>(O, slotmap, y);
}